// Round 2
// baseline (83.094 us; speedup 1.0000x reference)
//
#include <hip/hip_runtime.h>
#include <hip/hip_bf16.h>
#include <math.h>

// DOSAConLoss, fully fused single-block kernel.
// loss_loc factorizes: mean_{i,j} [A_i * B_j] = (ΣA)(ΣB)/N², where
//   A_i = (1+1.2*dens_i) * sigmoid(5*(0.5-ciou_i)) * (1-ciou_i)^2.5
//   B_j = 1/(w_j*h_j + 1e-7)
// plus P=100 contrastive pairs (plain IoU gate + embedding-distance hinge²).
// Work is ~0.75 MB reads + ~1 MFLOP -> launch/latency bound; one block of
// 1024 threads (16 waves) does everything, no workspace, one graph node.

#define NTHR 1024

__device__ __forceinline__ float iou_plain(float4 b1, float4 b2) {
    float b1x1 = b1.x - 0.5f * b1.z, b1x2 = b1.x + 0.5f * b1.z;
    float b1y1 = b1.y - 0.5f * b1.w, b1y2 = b1.y + 0.5f * b1.w;
    float b2x1 = b2.x - 0.5f * b2.z, b2x2 = b2.x + 0.5f * b2.z;
    float b2y1 = b2.y - 0.5f * b2.w, b2y2 = b2.y + 0.5f * b2.w;
    float iw = fmaxf(fminf(b1x2, b2x2) - fmaxf(b1x1, b2x1), 0.0f);
    float ih = fmaxf(fminf(b1y2, b2y2) - fmaxf(b1y1, b2y1), 0.0f);
    float inter = iw * ih;
    float uni = b1.z * b1.w + b2.z * b2.w - inter + 1e-7f;
    return inter / uni;
}

__device__ __forceinline__ float iou_ciou(float4 b1, float4 b2) {
    float b1x1 = b1.x - 0.5f * b1.z, b1x2 = b1.x + 0.5f * b1.z;
    float b1y1 = b1.y - 0.5f * b1.w, b1y2 = b1.y + 0.5f * b1.w;
    float b2x1 = b2.x - 0.5f * b2.z, b2x2 = b2.x + 0.5f * b2.z;
    float b2y1 = b2.y - 0.5f * b2.w, b2y2 = b2.y + 0.5f * b2.w;
    float iw = fmaxf(fminf(b1x2, b2x2) - fmaxf(b1x1, b2x1), 0.0f);
    float ih = fmaxf(fminf(b1y2, b2y2) - fmaxf(b1y1, b2y1), 0.0f);
    float inter = iw * ih;
    float uni = b1.z * b1.w + b2.z * b2.w - inter + 1e-7f;
    float iou = inter / uni;
    float cw = fmaxf(b1x2, b2x2) - fminf(b1x1, b2x1);
    float ch = fmaxf(b1y2, b2y2) - fminf(b1y1, b2y1);
    float c2 = cw * cw + ch * ch + 1e-7f;
    // rho2 = ((2x2-2x1)^2 + (2y2-2y1)^2)/4 = (cx2-cx1)^2 + (cy2-cy1)^2
    float dx = b2.x - b1.x, dy = b2.y - b1.y;
    float rho2 = dx * dx + dy * dy;
    float dat = atanf(b2.z / b2.w) - atanf(b1.z / b1.w);
    const float four_over_pi2 = 0.40528473456935108578f; // 4/pi^2
    float v = four_over_pi2 * dat * dat;
    float alpha = v / (v - iou + (1.0f + 1e-7f));
    return iou - (rho2 / c2 + v * alpha);
}

__global__ __launch_bounds__(NTHR) void fused_kernel(
    const float4* __restrict__ pred, const float4* __restrict__ targ,
    const float* __restrict__ emb, const float* __restrict__ dens,
    const int* __restrict__ idx, float* __restrict__ out, int N, int P) {
    int tid = threadIdx.x;
    int lane = tid & 63;
    int wid = tid >> 6;   // 0..15

    float sA = 0.0f, sB = 0.0f, sC = 0.0f;

    // --- loc part: 8 iterations per thread at N=8192 ---
    #pragma unroll 4
    for (int i = tid; i < N; i += NTHR) {
        float4 pb = pred[i];
        float4 tb = targ[i];
        float dn = dens[i];
        float iou = iou_ciou(pb, tb);
        float om = fmaxf(1.0f - iou, 0.0f);   // >=0 analytically; guard fp noise
        float saf = om * om * sqrtf(om);      // om^2.5
        float hw = 1.0f / (1.0f + expf(5.0f * iou - 2.5f)); // sigmoid(5*(0.5-iou))
        sA += (1.0f + 1.2f * dn) * hw * saf;
        sB += 1.0f / (tb.z * tb.w + 1e-7f);
    }

    // --- contrastive part: 16 waves cycle over P pairs ---
    for (int p = wid; p < P; p += (NTHR / 64)) {
        int i0 = idx[2 * p];
        int i1 = idx[2 * p + 1];
        float4 a = ((const float4*)(emb + (size_t)i0 * 256))[lane];
        float4 b = ((const float4*)(emb + (size_t)i1 * 256))[lane];
        float dx = a.x - b.x, dy = a.y - b.y, dz = a.z - b.z, dw = a.w - b.w;
        float d2 = dx * dx + dy * dy + dz * dz + dw * dw;
        #pragma unroll
        for (int o = 32; o > 0; o >>= 1) d2 += __shfl_xor(d2, o);
        if (lane == 0) {
            float dist = sqrtf(d2);
            float pl = fmaxf(1.0f - dist, 0.0f);
            pl = pl * pl;
            float piou = iou_plain(pred[i0], pred[i1]);
            if (piou > 0.3f) sC += pl;
        }
    }

    // --- block reduction: 16 waves -> scalar ---
    #pragma unroll
    for (int o = 32; o > 0; o >>= 1) {
        sA += __shfl_xor(sA, o);
        sB += __shfl_xor(sB, o);
        sC += __shfl_xor(sC, o);
    }
    __shared__ float red[NTHR / 64][3];
    if (lane == 0) {
        red[wid][0] = sA; red[wid][1] = sB; red[wid][2] = sC;
    }
    __syncthreads();
    if (tid == 0) {
        float a = 0.0f, b = 0.0f, c = 0.0f;
        #pragma unroll
        for (int w = 0; w < NTHR / 64; w++) {
            a += red[w][0]; b += red[w][1]; c += red[w][2];
        }
        float n2 = (float)N * (float)N;
        out[0] = (a * b) / n2 + 0.5f * c / ((float)P + 1e-7f);
    }
}

extern "C" void kernel_launch(void* const* d_in, const int* in_sizes, int n_in,
                              void* d_out, int out_size, void* d_ws, size_t ws_size,
                              hipStream_t stream) {
    const float4* pred = (const float4*)d_in[0];
    const float4* targ = (const float4*)d_in[1];
    const float* emb   = (const float*)d_in[2];
    const float* dens  = (const float*)d_in[3];
    const int* idx     = (const int*)d_in[4];
    float* out = (float*)d_out;

    int N = in_sizes[0] / 4;   // 8192
    int P = in_sizes[4] / 2;   // 100

    fused_kernel<<<1, NTHR, 0, stream>>>(pred, targ, emb, dens, idx, out, N, P);
}

// Round 3
// 66.665 us; speedup vs baseline: 1.2464x; 1.2464x over previous
//
#include <hip/hip_runtime.h>
#include <hip/hip_bf16.h>
#include <math.h>

// DOSAConLoss, single-kernel multi-block with last-block (flag-based) finalize.
// loss_loc factorizes: mean_{i,j}[A_i * B_j] = (ΣA)(ΣB)/N², where
//   A_i = (1+1.2*dens_i) * sigmoid(5*(0.5-ciou_i)) * (1-ciou_i)^2.5
//   B_j = 1/(w_j*h_j + 1e-7)
// plus P=100 contrastive pairs (plain IoU gate + embedding hinge²).
// 64 blocks spread the ~500 KB of reads over 64 CUs (round 2 showed one CU is
// ~2x slower than the whole two-kernel pipeline). Block 0 spin-waits on
// device-scope flags (poison 0xAAAAAAAA != 1, so no zero-init needed) and
// finalizes — one graph node total.

#define NBLK 64
#define NTHR 256

__device__ __forceinline__ float iou_plain(float4 b1, float4 b2) {
    float b1x1 = b1.x - 0.5f * b1.z, b1x2 = b1.x + 0.5f * b1.z;
    float b1y1 = b1.y - 0.5f * b1.w, b1y2 = b1.y + 0.5f * b1.w;
    float b2x1 = b2.x - 0.5f * b2.z, b2x2 = b2.x + 0.5f * b2.z;
    float b2y1 = b2.y - 0.5f * b2.w, b2y2 = b2.y + 0.5f * b2.w;
    float iw = fmaxf(fminf(b1x2, b2x2) - fmaxf(b1x1, b2x1), 0.0f);
    float ih = fmaxf(fminf(b1y2, b2y2) - fmaxf(b1y1, b2y1), 0.0f);
    float inter = iw * ih;
    float uni = b1.z * b1.w + b2.z * b2.w - inter + 1e-7f;
    return inter / uni;
}

__device__ __forceinline__ float iou_ciou(float4 b1, float4 b2) {
    float b1x1 = b1.x - 0.5f * b1.z, b1x2 = b1.x + 0.5f * b1.z;
    float b1y1 = b1.y - 0.5f * b1.w, b1y2 = b1.y + 0.5f * b1.w;
    float b2x1 = b2.x - 0.5f * b2.z, b2x2 = b2.x + 0.5f * b2.z;
    float b2y1 = b2.y - 0.5f * b2.w, b2y2 = b2.y + 0.5f * b2.w;
    float iw = fmaxf(fminf(b1x2, b2x2) - fmaxf(b1x1, b2x1), 0.0f);
    float ih = fmaxf(fminf(b1y2, b2y2) - fmaxf(b1y1, b2y1), 0.0f);
    float inter = iw * ih;
    float uni = b1.z * b1.w + b2.z * b2.w - inter + 1e-7f;
    float iou = inter / uni;
    float cw = fmaxf(b1x2, b2x2) - fminf(b1x1, b2x1);
    float ch = fmaxf(b1y2, b2y2) - fminf(b1y1, b2y1);
    float c2 = cw * cw + ch * ch + 1e-7f;
    float dx = b2.x - b1.x, dy = b2.y - b1.y;
    float rho2 = dx * dx + dy * dy;   // ((sum-corner diff)^2)/4 == center-dist^2
    float dat = atanf(b2.z / b2.w) - atanf(b1.z / b1.w);
    const float four_over_pi2 = 0.40528473456935108578f; // 4/pi^2
    float v = four_over_pi2 * dat * dat;
    float alpha = v / (v - iou + (1.0f + 1e-7f));
    return iou - (rho2 / c2 + v * alpha);
}

__global__ __launch_bounds__(NTHR) void fused_kernel(
    const float4* __restrict__ pred, const float4* __restrict__ targ,
    const float* __restrict__ emb, const float* __restrict__ dens,
    const int* __restrict__ idx, float* __restrict__ out,
    float* __restrict__ ws, int N, int P) {
    int tid = threadIdx.x;
    int bid = blockIdx.x;
    int gtid = bid * NTHR + tid;
    int lane = tid & 63;
    int wid = tid >> 6;

    float sA = 0.0f, sB = 0.0f, sC = 0.0f;

    // --- loc part: 16384 threads over N=8192 (each <=1 element) ---
    for (int i = gtid; i < N; i += NBLK * NTHR) {
        float4 pb = pred[i];
        float4 tb = targ[i];
        float dn = dens[i];
        float iou = iou_ciou(pb, tb);
        float om = fmaxf(1.0f - iou, 0.0f);
        float saf = om * om * sqrtf(om);                    // om^2.5
        float hw = 1.0f / (1.0f + expf(5.0f * iou - 2.5f)); // sigmoid(5*(0.5-iou))
        sA += (1.0f + 1.2f * dn) * hw * saf;
        sB += 1.0f / (tb.z * tb.w + 1e-7f);
    }

    // --- contrastive part: 256 waves, one per pair (P=100 used) ---
    int gwid = gtid >> 6;
    for (int p = gwid; p < P; p += NBLK * (NTHR / 64)) {
        int i0 = idx[2 * p];
        int i1 = idx[2 * p + 1];
        float4 a = ((const float4*)(emb + (size_t)i0 * 256))[lane];
        float4 b = ((const float4*)(emb + (size_t)i1 * 256))[lane];
        float dx = a.x - b.x, dy = a.y - b.y, dz = a.z - b.z, dw = a.w - b.w;
        float d2 = dx * dx + dy * dy + dz * dz + dw * dw;
        #pragma unroll
        for (int o = 32; o > 0; o >>= 1) d2 += __shfl_xor(d2, o);
        if (lane == 0) {
            float dist = sqrtf(d2);
            float pl = fmaxf(1.0f - dist, 0.0f);
            pl = pl * pl;
            float piou = iou_plain(pred[i0], pred[i1]);
            if (piou > 0.3f) sC += pl;
        }
    }

    // --- block reduction: 4 waves -> block partials ---
    #pragma unroll
    for (int o = 32; o > 0; o >>= 1) {
        sA += __shfl_xor(sA, o);
        sB += __shfl_xor(sB, o);
        sC += __shfl_xor(sC, o);
    }
    __shared__ float red[NTHR / 64][3];
    if (lane == 0) { red[wid][0] = sA; red[wid][1] = sB; red[wid][2] = sC; }
    __syncthreads();

    // ws layout (floats): A[0..63] B[64..127] C[128..191]; flags u32 [192..255]
    unsigned int* flags = (unsigned int*)ws + 3 * NBLK;
    if (tid == 0) {
        float a = 0.0f, b = 0.0f, c = 0.0f;
        #pragma unroll
        for (int w = 0; w < NTHR / 64; w++) { a += red[w][0]; b += red[w][1]; c += red[w][2]; }
        // agent-scope release stores: partials visible before flag across XCDs
        __hip_atomic_store(&ws[bid],            a, __ATOMIC_RELAXED, __HIP_MEMORY_SCOPE_AGENT);
        __hip_atomic_store(&ws[NBLK + bid],     b, __ATOMIC_RELAXED, __HIP_MEMORY_SCOPE_AGENT);
        __hip_atomic_store(&ws[2 * NBLK + bid], c, __ATOMIC_RELAXED, __HIP_MEMORY_SCOPE_AGENT);
        __hip_atomic_store(&flags[bid], 1u, __ATOMIC_RELEASE, __HIP_MEMORY_SCOPE_AGENT);
    }

    // --- block 0, wave 0: spin on all 64 flags, then finalize ---
    if (bid == 0 && tid < 64) {
        while (__hip_atomic_load(&flags[lane], __ATOMIC_ACQUIRE, __HIP_MEMORY_SCOPE_AGENT) != 1u) {
            __builtin_amdgcn_s_sleep(1);
        }
        float a = __hip_atomic_load(&ws[lane],            __ATOMIC_RELAXED, __HIP_MEMORY_SCOPE_AGENT);
        float b = __hip_atomic_load(&ws[NBLK + lane],     __ATOMIC_RELAXED, __HIP_MEMORY_SCOPE_AGENT);
        float c = __hip_atomic_load(&ws[2 * NBLK + lane], __ATOMIC_RELAXED, __HIP_MEMORY_SCOPE_AGENT);
        #pragma unroll
        for (int o = 32; o > 0; o >>= 1) {
            a += __shfl_xor(a, o);
            b += __shfl_xor(b, o);
            c += __shfl_xor(c, o);
        }
        if (lane == 0) {
            float n2 = (float)N * (float)N;
            out[0] = (a * b) / n2 + 0.5f * c / ((float)P + 1e-7f);
        }
    }
}

extern "C" void kernel_launch(void* const* d_in, const int* in_sizes, int n_in,
                              void* d_out, int out_size, void* d_ws, size_t ws_size,
                              hipStream_t stream) {
    const float4* pred = (const float4*)d_in[0];
    const float4* targ = (const float4*)d_in[1];
    const float* emb   = (const float*)d_in[2];
    const float* dens  = (const float*)d_in[3];
    const int* idx     = (const int*)d_in[4];
    float* out = (float*)d_out;
    float* ws  = (float*)d_ws;

    int N = in_sizes[0] / 4;   // 8192
    int P = in_sizes[4] / 2;   // 100

    fused_kernel<<<NBLK, NTHR, 0, stream>>>(pred, targ, emb, dens, idx, out, ws, N, P);
}